// Round 6
// baseline (657.439 us; speedup 1.0000x reference)
//
#include <hip/hip_runtime.h>
#include <hip/hip_bf16.h>
#include <cstdint>
#include <cstddef>

// Problem constants (match reference)
#define BB 2
#define LL 2048
#define DM 1024
#define DI 2048
#define DS 16
#define MM (BB*LL)       // 4096 rows
#define NCAT 2176        // 2048 (W_dt) + 32 (W_x) + 96 pad -> 17 tiles of 128
#define NC 8             // scan chunks (parallel-scan over L)
#define LC (LL/NC)       // 256 timesteps per chunk

typedef __attribute__((ext_vector_type(8))) short short8;   // 8 x bf16 fragment
typedef __attribute__((ext_vector_type(4))) float f32x4;    // MFMA accumulator

__device__ __forceinline__ unsigned short f2bf(float f) {
  union { float f; unsigned int u; } x; x.f = f;
  unsigned int u = x.u;
  unsigned int r = (u + 0x7FFFu + ((u >> 16) & 1u)) >> 16;  // RNE
  return (unsigned short)r;
}

// ---------------- cast fp32 -> bf16 (vectorized) ----------------
__global__ __launch_bounds__(256) void cast_bf16_k(const float* __restrict__ in,
                                                   unsigned short* __restrict__ out, int n) {
  int i = (blockIdx.x * 256 + threadIdx.x) * 4;
  if (i < n) {
    float4 v = *(const float4*)&in[i];
    ushort4 o;
    o.x = f2bf(v.x); o.y = f2bf(v.y); o.z = f2bf(v.z); o.w = f2bf(v.w);
    *(ushort4*)&out[i] = o;
  }
}

// ---------------- transpose + cast: W (RxC f32) -> WT (CxR bf16) ----------------
__global__ __launch_bounds__(256) void transpose_cast_k(const float* __restrict__ W,
                                                        unsigned short* __restrict__ WT,
                                                        int R, int C) {
  __shared__ float tile[32][33];
  int c0 = blockIdx.x * 32;
  int r0 = blockIdx.y * 32;
  int tx = threadIdx.x;        // 0..31
  int ty = threadIdx.y;        // 0..7
#pragma unroll
  for (int i = 0; i < 4; ++i) {
    int r = r0 + ty + i * 8;
    tile[ty + i * 8][tx] = W[(size_t)r * C + c0 + tx];
  }
  __syncthreads();
#pragma unroll
  for (int i = 0; i < 4; ++i) {
    int c = c0 + ty + i * 8;
    WT[(size_t)c * R + r0 + tx] = f2bf(tile[tx][ty + i * 8]);
  }
}

// ---------------- bf16 MFMA GEMM, C = A * Bt^T ----------------
// A: M x K bf16 row-major. Bt: N x K bf16 row-major (i.e. B transposed).
// MODE 0: plain fp32 store to C (ldc = N)
// MODE 1: split epilogue: col < nSplit -> softplus(v + bias[col]) into C (ldc = nSplit);
//         nSplit <= col < nSplit+32 -> raw v into C2 (ldc = 32); else drop.
#define BM 128
#define BN 128
#define BK 32
template <int MODE>
__global__ __launch_bounds__(256) void gemm_bt_k(const unsigned short* __restrict__ A,
                                                 const unsigned short* __restrict__ Bt,
                                                 float* __restrict__ C,
                                                 int M, int N, int K,
                                                 const float* __restrict__ bias,
                                                 float* __restrict__ C2, int nSplit) {
  __shared__ unsigned short As[BM * BK];   // 8 KB
  __shared__ unsigned short Bs[BN * BK];   // 8 KB
  const int tid  = threadIdx.x;
  const int lane = tid & 63;
  const int wv   = tid >> 6;               // wave 0..3
  const int nTilesN = N / BN;
  const int bm = (blockIdx.x / nTilesN) * BM;
  const int bn = (blockIdx.x % nTilesN) * BN;
  const int wr = wv >> 1, wc = wv & 1;     // 2x2 wave grid, each wave 64x64

  f32x4 acc[4][4] = {};

  const int nK = K / BK;
  for (int kt = 0; kt < nK; ++kt) {
    const int k0 = kt * BK;
    // stage A and B tiles: 8 chunks of 1KB each (wave-uniform LDS dest + lane*16B)
#pragma unroll
    for (int r = 0; r < 2; ++r) {
      int chunk = r * 4 + wv;              // 0..7
      int eidx  = chunk * 64 + lane;       // 16-byte unit index 0..511
      int row   = eidx >> 2;               // 0..127
      int col   = (eidx & 3) * 8;          // bf16 elements
      const unsigned short* gA = A  + (size_t)(bm + row) * K + k0 + col;
      const unsigned short* gB = Bt + (size_t)(bn + row) * K + k0 + col;
      __builtin_amdgcn_global_load_lds(
          (const __attribute__((address_space(1))) unsigned int*)gA,
          (__attribute__((address_space(3))) unsigned int*)&As[chunk * 512], 16, 0, 0);
      __builtin_amdgcn_global_load_lds(
          (const __attribute__((address_space(1))) unsigned int*)gB,
          (__attribute__((address_space(3))) unsigned int*)&Bs[chunk * 512], 16, 0, 0);
    }
    __syncthreads();   // drains vmcnt + barrier

    short8 af[4], bf[4];
    const int kofs = (lane >> 4) * 8;
#pragma unroll
    for (int i = 0; i < 4; ++i) {
      int ar = wr * 64 + i * 16 + (lane & 15);
      af[i] = *(const short8*)&As[ar * BK + kofs];
      int br = wc * 64 + i * 16 + (lane & 15);
      bf[i] = *(const short8*)&Bs[br * BK + kofs];
    }
#pragma unroll
    for (int i = 0; i < 4; ++i)
#pragma unroll
      for (int j = 0; j < 4; ++j)
        acc[i][j] = __builtin_amdgcn_mfma_f32_16x16x32_bf16(af[i], bf[j], acc[i][j], 0, 0, 0);
    __syncthreads();
  }

  // epilogue: C/D layout col = lane&15, row = (lane>>4)*4 + r
  const int colBase = bn + wc * 64;
  const int rowBase = bm + wr * 64;
#pragma unroll
  for (int i = 0; i < 4; ++i) {
#pragma unroll
    for (int j = 0; j < 4; ++j) {
      int c = colBase + j * 16 + (lane & 15);
#pragma unroll
      for (int r4 = 0; r4 < 4; ++r4) {
        int rr = rowBase + i * 16 + (lane >> 4) * 4 + r4;
        float v = acc[i][j][r4];
        if (MODE == 0) {
          C[(size_t)rr * N + c] = v;
        } else {
          if (c < nSplit) {
            float t = v + bias[c];
            C[(size_t)rr * nSplit + c] = (t > 20.f) ? t : log1pf(expf(t));
          } else if (c < nSplit + 32) {
            C2[(size_t)rr * 32 + (c - nSplit)] = v;
          }
        }
      }
    }
  }
}

// ---------------- causal depthwise conv (K=4) + SiLU, x4 channels/thread ----------------
// xz: (B, L, 4096) fp32; xp = xz[:, :, 0:2048]. Writes xc fp32 and bf16.
__global__ __launch_bounds__(256) void conv_silu_k(const float* __restrict__ xz,
                                                   const float* __restrict__ cw,
                                                   const float* __restrict__ cb,
                                                   float* __restrict__ xc,
                                                   unsigned short* __restrict__ xcb) {
  int idx = blockIdx.x * 256 + threadIdx.x;          // B*L*DI/4 threads
  int i4  = idx * 4;
  int c4  = i4 & (DI - 1);                           // channel base (multiple of 4)
  int row = i4 >> 11;                                // b*L + t
  int t   = row & (LL - 1);
  size_t base = (size_t)row * 4096 + c4;
  // taps: 4 channels x 4 timesteps
  float4 x3 = *(const float4*)&xz[base];             // tap at l (w3)
  float4 x2 = (t >= 1) ? *(const float4*)&xz[base - 4096]  : float4{0, 0, 0, 0};
  float4 x1 = (t >= 2) ? *(const float4*)&xz[base - 8192]  : float4{0, 0, 0, 0};
  float4 x0 = (t >= 3) ? *(const float4*)&xz[base - 12288] : float4{0, 0, 0, 0};
  float4 bias = *(const float4*)&cb[c4];
  float4 w[4];                                       // w[j] = taps of channel c4+j
#pragma unroll
  for (int j = 0; j < 4; ++j) w[j] = *(const float4*)&cw[(c4 + j) * 4];
  float vx3[4] = {x3.x, x3.y, x3.z, x3.w};
  float vx2[4] = {x2.x, x2.y, x2.z, x2.w};
  float vx1[4] = {x1.x, x1.y, x1.z, x1.w};
  float vx0[4] = {x0.x, x0.y, x0.z, x0.w};
  float vb[4]  = {bias.x, bias.y, bias.z, bias.w};
  float4 so;
  ushort4 sb;
  float res[4];
#pragma unroll
  for (int j = 0; j < 4; ++j) {
    float v = vb[j];
    v = fmaf(vx3[j], w[j].w, v);
    v = fmaf(vx2[j], w[j].z, v);
    v = fmaf(vx1[j], w[j].y, v);
    v = fmaf(vx0[j], w[j].x, v);
    res[j] = v / (1.f + expf(-v));                   // SiLU
  }
  so.x = res[0]; so.y = res[1]; so.z = res[2]; so.w = res[3];
  sb.x = f2bf(res[0]); sb.y = f2bf(res[1]); sb.z = f2bf(res[2]); sb.w = f2bf(res[3]);
  *(float4*)&xc[i4] = so;
  *(ushort4*)&xcb[i4] = sb;
}

// ---------------- parallel selective scan, pass 1 ----------------
// Chunked scan over L (h is linear in chunk-entry state): each chunk scans from
// h=0 recording decay product P = prod(dA) and partial state S = h_end.
// Layout of P/S: (b, chunk, d, s). lane = (ch_local, state) as in pass 2.
__global__ __launch_bounds__(256) void scan1_k(const float* __restrict__ dt,
                                               const float* __restrict__ u,
                                               const float* __restrict__ BC,
                                               const float* __restrict__ A_log,
                                               float* __restrict__ Pc,
                                               float* __restrict__ Sc) {
  int lane = threadIdx.x & 63;
  int wv   = threadIdx.x >> 6;
  int b    = blockIdx.y;
  int cg   = blockIdx.x / NC;          // channel group 0..127
  int nc   = blockIdx.x % NC;          // chunk 0..7
  int d    = cg * 16 + wv * 4 + (lane >> 4);
  int s    = lane & 15;
  float A2 = -expf(A_log[d * DS + s]) * 1.44269504088896340736f;  // A * log2(e)
  float h  = 0.f, P = 1.f;
  const int t0 = nc * LC;
  const float* dtp = dt + ((size_t)b * LL + t0) * DI + d;
  const float* up  = u  + ((size_t)b * LL + t0) * DI + d;
  const float* bcp = BC + ((size_t)b * LL + t0) * 32;
  for (int t = 0; t < LC; ++t) {
    float dtv = dtp[(size_t)t * DI];
    float uv  = up[(size_t)t * DI];
    float Bv  = bcp[t * 32 + s];
    float dA  = exp2f(dtv * A2);
    h = fmaf(dA, h, dtv * uv * Bv);
    P *= dA;                            // underflow to 0 is benign (fully-decayed state)
  }
  size_t o = (((size_t)b * NC + nc) * DI + d) * DS + s;   // coalesced per wave
  Pc[o] = P;
  Sc[o] = h;
}

// ---------------- parallel selective scan, pass 2 (+ gate + bf16 cast) ----------------
// Stitch h0 from chunks j<nc (h_{after j} = P_j*h + S_j, j ascending), then re-scan
// own chunk emitting y. Within-chunk op sequence identical to the sequential scan.
__global__ __launch_bounds__(256) void scan2_k(const float* __restrict__ dt,
                                               const float* __restrict__ u,
                                               const float* __restrict__ BC,
                                               const float* __restrict__ xz,
                                               const float* __restrict__ A_log,
                                               const float* __restrict__ Dp,
                                               const float* __restrict__ Pc,
                                               const float* __restrict__ Sc,
                                               unsigned short* __restrict__ ymb) {
  int lane = threadIdx.x & 63;
  int wv   = threadIdx.x >> 6;
  int b    = blockIdx.y;
  int cg   = blockIdx.x / NC;
  int nc   = blockIdx.x % NC;
  int d    = cg * 16 + wv * 4 + (lane >> 4);
  int s    = lane & 15;
  float A2 = -expf(A_log[d * DS + s]) * 1.44269504088896340736f;
  float Dd = Dp[d];
  // stitch chunk-entry state from pass-1 partials (uniform loop per block)
  float h = 0.f;
  size_t pbase = (((size_t)b * NC) * DI + d) * DS + s;
  for (int j = 0; j < nc; ++j) {
    float Pj = Pc[pbase + (size_t)j * DI * DS];
    float Sj = Sc[pbase + (size_t)j * DI * DS];
    h = fmaf(Pj, h, Sj);
  }
  const int t0 = nc * LC;
  const float* dtp = dt + ((size_t)b * LL + t0) * DI + d;
  const float* up  = u  + ((size_t)b * LL + t0) * DI + d;
  const float* bcp = BC + ((size_t)b * LL + t0) * 32;
  const float* zp  = xz + ((size_t)b * LL + t0) * 4096 + DI + d;
  unsigned short* yp = ymb + ((size_t)b * LL + t0) * DI + d;
  for (int t = 0; t < LC; ++t) {
    float dtv = dtp[(size_t)t * DI];
    float uv  = up[(size_t)t * DI];
    float Bv  = bcp[t * 32 + s];
    float Cv  = bcp[t * 32 + 16 + s];
    float dA  = exp2f(dtv * A2);
    h = fmaf(dA, h, dtv * uv * Bv);
    float c = h * Cv;
    c += __shfl_xor(c, 1);
    c += __shfl_xor(c, 2);
    c += __shfl_xor(c, 4);
    c += __shfl_xor(c, 8);
    if (s == 0) {
      float zv = zp[(size_t)t * 4096];
      float y  = fmaf(Dd, uv, c);
      float sz = zv / (1.f + expf(-zv));
      yp[(size_t)t * DI] = f2bf(y * sz);
    }
  }
}

extern "C" void kernel_launch(void* const* d_in, const int* in_sizes, int n_in,
                              void* d_out, int out_size, void* d_ws, size_t ws_size,
                              hipStream_t stream) {
  const float* x      = (const float*)d_in[0];
  const float* W_in   = (const float*)d_in[1];
  const float* conv_w = (const float*)d_in[2];
  const float* conv_b = (const float*)d_in[3];
  const float* W_x    = (const float*)d_in[4];
  const float* W_dt   = (const float*)d_in[5];
  const float* b_dt   = (const float*)d_in[6];
  const float* A_log  = (const float*)d_in[7];
  const float* Dv     = (const float*)d_in[8];
  const float* W_out  = (const float*)d_in[9];
  float* out = (float*)d_out;

  // workspace carve-up (~193 MB)
  char* w = (char*)d_ws;
  float* xz  = (float*)w;            w += (size_t)MM * 4096 * 4;   // 64 MB
  float* xc  = (float*)w;            w += (size_t)MM * DI * 4;     // 32 MB
  float* dtb = (float*)w;            w += (size_t)MM * DI * 4;     // 32 MB
  float* BC  = (float*)w;            w += (size_t)MM * 32 * 4;     // 0.5 MB
  float* Pc  = (float*)w;            w += (size_t)BB * NC * DI * DS * 4;  // 2 MB
  float* Sc  = (float*)w;            w += (size_t)BB * NC * DI * DS * 4;  // 2 MB
  unsigned short* x_b   = (unsigned short*)w; w += (size_t)MM * DM * 2;    // 8 MB
  unsigned short* xc_b  = (unsigned short*)w; w += (size_t)MM * DI * 2;    // 16 MB
  unsigned short* ym_b  = (unsigned short*)w; w += (size_t)MM * DI * 2;    // 16 MB
  unsigned short* WinT  = (unsigned short*)w; w += (size_t)(2 * DI) * DM * 2;  // 8 MB (4096 x 1024)
  unsigned short* WcatT = (unsigned short*)w; w += (size_t)NCAT * DI * 2;      // 8.5 MB (2176 x 2048)
  unsigned short* WoutT = (unsigned short*)w; w += (size_t)DM * DI * 2;        // 4 MB (1024 x 2048)

  // 1) casts + weight transposes (bf16, B^T layout for gemm_bt)
  cast_bf16_k<<<(MM * DM) / 1024, 256, 0, stream>>>(x, x_b, MM * DM);
  transpose_cast_k<<<dim3(4096 / 32, DM / 32), dim3(32, 8), 0, stream>>>(W_in, WinT, DM, 4096);
  transpose_cast_k<<<dim3(DI / 32, DI / 32), dim3(32, 8), 0, stream>>>(W_dt, WcatT, DI, DI);
  transpose_cast_k<<<dim3(1, DI / 32), dim3(32, 8), 0, stream>>>(W_x, WcatT + (size_t)DI * DI, DI, 32);
  hipMemsetAsync(WcatT + (size_t)(DI + 32) * DI, 0, (size_t)(NCAT - DI - 32) * DI * 2, stream);
  transpose_cast_k<<<dim3(DM / 32, DI / 32), dim3(32, 8), 0, stream>>>(W_out, WoutT, DI, DM);

  // 2) xz = x @ W_in   (4096 x 4096, K=1024)
  gemm_bt_k<0><<<(MM / BM) * (4096 / BN), 256, 0, stream>>>(x_b, WinT, xz, MM, 4096, DM,
                                                            nullptr, nullptr, 0);
  // 3) xc = silu(conv(xp))  -- 4 channels per thread
  conv_silu_k<<<(MM * DI) / 1024, 256, 0, stream>>>(xz, conv_w, conv_b, xc, xc_b);

  // 4) [dt | BC] = xc @ [W_dt | W_x] with softplus+bias epilogue on dt half
  gemm_bt_k<1><<<(MM / BM) * (NCAT / BN), 256, 0, stream>>>(xc_b, WcatT, dtb, MM, NCAT, DI,
                                                            b_dt, BC, DI);
  // 5) chunked parallel selective scan + D*u + silu(z) gate -> ym (bf16)
  scan1_k<<<dim3((DI / 16) * NC, BB), 256, 0, stream>>>(dtb, xc, BC, A_log, Pc, Sc);
  scan2_k<<<dim3((DI / 16) * NC, BB), 256, 0, stream>>>(dtb, xc, BC, xz, A_log, Dv, Pc, Sc, ym_b);

  // 6) out = ym @ W_out  (4096 x 1024, K=2048)
  gemm_bt_k<0><<<(MM / BM) * (DM / BN), 256, 0, stream>>>(ym_b, WoutT, out, MM, DM, DI,
                                                          nullptr, nullptr, 0);
}

// Round 8
// 489.730 us; speedup vs baseline: 1.3425x; 1.3425x over previous
//
#include <hip/hip_runtime.h>
#include <hip/hip_bf16.h>
#include <cstdint>
#include <cstddef>

// Problem constants (match reference)
#define BB 2
#define LL 2048
#define DM 1024
#define DI 2048
#define DS 16
#define MM (BB*LL)       // 4096 rows
#define NCAT 2176        // 2048 (W_dt) + 32 (W_x) + 96 pad -> 17 tiles of 128
#define NC 32            // scan chunks (parallel-scan over L)
#define LC (LL/NC)       // 64 timesteps per chunk

typedef __attribute__((ext_vector_type(8))) short short8;   // 8 x bf16 fragment
typedef __attribute__((ext_vector_type(4))) float f32x4;    // MFMA accumulator

__device__ __forceinline__ unsigned short f2bf(float f) {
  union { float f; unsigned int u; } x; x.f = f;
  unsigned int u = x.u;
  unsigned int r = (u + 0x7FFFu + ((u >> 16) & 1u)) >> 16;  // RNE
  return (unsigned short)r;
}

// ---------------- cast fp32 -> bf16 (vectorized) ----------------
__global__ __launch_bounds__(256) void cast_bf16_k(const float* __restrict__ in,
                                                   unsigned short* __restrict__ out, int n) {
  int i = (blockIdx.x * 256 + threadIdx.x) * 4;
  if (i < n) {
    float4 v = *(const float4*)&in[i];
    ushort4 o;
    o.x = f2bf(v.x); o.y = f2bf(v.y); o.z = f2bf(v.z); o.w = f2bf(v.w);
    *(ushort4*)&out[i] = o;
  }
}

// ---------------- transpose + cast: W (RxC f32) -> WT (CxR bf16) ----------------
__global__ __launch_bounds__(256) void transpose_cast_k(const float* __restrict__ W,
                                                        unsigned short* __restrict__ WT,
                                                        int R, int C) {
  __shared__ float tile[32][33];
  int c0 = blockIdx.x * 32;
  int r0 = blockIdx.y * 32;
  int tx = threadIdx.x;        // 0..31
  int ty = threadIdx.y;        // 0..7
#pragma unroll
  for (int i = 0; i < 4; ++i) {
    int r = r0 + ty + i * 8;
    tile[ty + i * 8][tx] = W[(size_t)r * C + c0 + tx];
  }
  __syncthreads();
#pragma unroll
  for (int i = 0; i < 4; ++i) {
    int c = c0 + ty + i * 8;
    WT[(size_t)c * R + r0 + tx] = f2bf(tile[tx][ty + i * 8]);
  }
}

// ---------------- bf16 MFMA GEMM, C = A * Bt^T ----------------
#define BM 128
#define BN 128
#define BK 32
template <int MODE>
__global__ __launch_bounds__(256) void gemm_bt_k(const unsigned short* __restrict__ A,
                                                 const unsigned short* __restrict__ Bt,
                                                 float* __restrict__ C,
                                                 int M, int N, int K,
                                                 const float* __restrict__ bias,
                                                 float* __restrict__ C2, int nSplit) {
  __shared__ unsigned short As[BM * BK];   // 8 KB
  __shared__ unsigned short Bs[BN * BK];   // 8 KB
  const int tid  = threadIdx.x;
  const int lane = tid & 63;
  const int wv   = tid >> 6;               // wave 0..3
  const int nTilesN = N / BN;
  const int bm = (blockIdx.x / nTilesN) * BM;
  const int bn = (blockIdx.x % nTilesN) * BN;
  const int wr = wv >> 1, wc = wv & 1;     // 2x2 wave grid, each wave 64x64

  f32x4 acc[4][4] = {};

  const int nK = K / BK;
  for (int kt = 0; kt < nK; ++kt) {
    const int k0 = kt * BK;
#pragma unroll
    for (int r = 0; r < 2; ++r) {
      int chunk = r * 4 + wv;              // 0..7
      int eidx  = chunk * 64 + lane;       // 16-byte unit index 0..511
      int row   = eidx >> 2;               // 0..127
      int col   = (eidx & 3) * 8;          // bf16 elements
      const unsigned short* gA = A  + (size_t)(bm + row) * K + k0 + col;
      const unsigned short* gB = Bt + (size_t)(bn + row) * K + k0 + col;
      __builtin_amdgcn_global_load_lds(
          (const __attribute__((address_space(1))) unsigned int*)gA,
          (__attribute__((address_space(3))) unsigned int*)&As[chunk * 512], 16, 0, 0);
      __builtin_amdgcn_global_load_lds(
          (const __attribute__((address_space(1))) unsigned int*)gB,
          (__attribute__((address_space(3))) unsigned int*)&Bs[chunk * 512], 16, 0, 0);
    }
    __syncthreads();   // drains vmcnt + barrier

    short8 af[4], bf[4];
    const int kofs = (lane >> 4) * 8;
#pragma unroll
    for (int i = 0; i < 4; ++i) {
      int ar = wr * 64 + i * 16 + (lane & 15);
      af[i] = *(const short8*)&As[ar * BK + kofs];
      int br = wc * 64 + i * 16 + (lane & 15);
      bf[i] = *(const short8*)&Bs[br * BK + kofs];
    }
#pragma unroll
    for (int i = 0; i < 4; ++i)
#pragma unroll
      for (int j = 0; j < 4; ++j)
        acc[i][j] = __builtin_amdgcn_mfma_f32_16x16x32_bf16(af[i], bf[j], acc[i][j], 0, 0, 0);
    __syncthreads();
  }

  // epilogue: C/D layout col = lane&15, row = (lane>>4)*4 + r
  const int colBase = bn + wc * 64;
  const int rowBase = bm + wr * 64;
#pragma unroll
  for (int i = 0; i < 4; ++i) {
#pragma unroll
    for (int j = 0; j < 4; ++j) {
      int c = colBase + j * 16 + (lane & 15);
#pragma unroll
      for (int r4 = 0; r4 < 4; ++r4) {
        int rr = rowBase + i * 16 + (lane >> 4) * 4 + r4;
        float v = acc[i][j][r4];
        if (MODE == 0) {
          C[(size_t)rr * N + c] = v;
        } else {
          if (c < nSplit) {
            float t = v + bias[c];
            C[(size_t)rr * nSplit + c] = (t > 20.f) ? t : log1pf(expf(t));
          } else if (c < nSplit + 32) {
            C2[(size_t)rr * 32 + (c - nSplit)] = v;
          }
        }
      }
    }
  }
}

// ---------------- causal depthwise conv (K=4) + SiLU, x4 channels/thread ----------------
__global__ __launch_bounds__(256) void conv_silu_k(const float* __restrict__ xz,
                                                   const float* __restrict__ cw,
                                                   const float* __restrict__ cb,
                                                   float* __restrict__ xc,
                                                   unsigned short* __restrict__ xcb) {
  int idx = blockIdx.x * 256 + threadIdx.x;          // B*L*DI/4 threads
  int i4  = idx * 4;
  int c4  = i4 & (DI - 1);                           // channel base (multiple of 4)
  int row = i4 >> 11;                                // b*L + t
  int t   = row & (LL - 1);
  size_t base = (size_t)row * 4096 + c4;
  float4 x3 = *(const float4*)&xz[base];             // tap at l (w3)
  float4 x2 = (t >= 1) ? *(const float4*)&xz[base - 4096]  : float4{0, 0, 0, 0};
  float4 x1 = (t >= 2) ? *(const float4*)&xz[base - 8192]  : float4{0, 0, 0, 0};
  float4 x0 = (t >= 3) ? *(const float4*)&xz[base - 12288] : float4{0, 0, 0, 0};
  float4 bias = *(const float4*)&cb[c4];
  float4 w[4];
#pragma unroll
  for (int j = 0; j < 4; ++j) w[j] = *(const float4*)&cw[(c4 + j) * 4];
  float vx3[4] = {x3.x, x3.y, x3.z, x3.w};
  float vx2[4] = {x2.x, x2.y, x2.z, x2.w};
  float vx1[4] = {x1.x, x1.y, x1.z, x1.w};
  float vx0[4] = {x0.x, x0.y, x0.z, x0.w};
  float vb[4]  = {bias.x, bias.y, bias.z, bias.w};
  float4 so;
  ushort4 sb;
  float res[4];
#pragma unroll
  for (int j = 0; j < 4; ++j) {
    float v = vb[j];
    v = fmaf(vx3[j], w[j].w, v);
    v = fmaf(vx2[j], w[j].z, v);
    v = fmaf(vx1[j], w[j].y, v);
    v = fmaf(vx0[j], w[j].x, v);
    res[j] = v / (1.f + expf(-v));                   // SiLU
  }
  so.x = res[0]; so.y = res[1]; so.z = res[2]; so.w = res[3];
  sb.x = f2bf(res[0]); sb.y = f2bf(res[1]); sb.z = f2bf(res[2]); sb.w = f2bf(res[3]);
  *(float4*)&xc[i4] = so;
  *(ushort4*)&xcb[i4] = sb;
}

// ---------------- parallel selective scan, pass 1 ----------------
// One lane per (b, d, chunk); all 16 states in registers; B via wave-uniform
// s_loads. Records chunk decay P[s] = exp2(A2[s]*sum(dt)) and partial state S.
// P/S layout: (b, chunk, d, s) -> per-lane 64B contiguous.
__global__ __launch_bounds__(256) void scan1_k(const float* __restrict__ dt,
                                               const float* __restrict__ u,
                                               const float* __restrict__ BC,
                                               const float* __restrict__ A_log,
                                               float* __restrict__ Pc,
                                               float* __restrict__ Sc) {
  int tid = threadIdx.x;
  int b   = blockIdx.y;
  int cg  = blockIdx.x / NC;           // channel group of 256
  int nc  = blockIdx.x % NC;           // chunk
  int d   = cg * 256 + tid;
  float A2[DS], h[DS];
#pragma unroll
  for (int s4 = 0; s4 < DS; s4 += 4) {
    float4 av = *(const float4*)&A_log[d * DS + s4];
    A2[s4 + 0] = -expf(av.x) * 1.44269504f;
    A2[s4 + 1] = -expf(av.y) * 1.44269504f;
    A2[s4 + 2] = -expf(av.z) * 1.44269504f;
    A2[s4 + 3] = -expf(av.w) * 1.44269504f;
    h[s4] = 0.f; h[s4 + 1] = 0.f; h[s4 + 2] = 0.f; h[s4 + 3] = 0.f;
  }
  float Tsum = 0.f;
  const int t0 = nc * LC;
  const float* dtp = dt + ((size_t)b * LL + t0) * DI + d;
  const float* up  = u  + ((size_t)b * LL + t0) * DI + d;
  const float* bcp = BC + ((size_t)b * LL + t0) * 32;     // wave-uniform -> SGPR
  for (int t = 0; t < LC; ++t) {
    float dtv = dtp[(size_t)t * DI];
    float uv  = up[(size_t)t * DI];
    float dtu = dtv * uv;
    Tsum += dtv;
#pragma unroll
    for (int s = 0; s < DS; ++s) {
      float dA = exp2f(dtv * A2[s]);
      h[s] = fmaf(dA, h[s], dtu * bcp[t * 32 + s]);
    }
  }
  size_t o = (((size_t)b * NC + nc) * DI + d) * DS;
#pragma unroll
  for (int s4 = 0; s4 < DS; s4 += 4) {
    float4 pv = {exp2f(A2[s4] * Tsum), exp2f(A2[s4 + 1] * Tsum),
                 exp2f(A2[s4 + 2] * Tsum), exp2f(A2[s4 + 3] * Tsum)};
    *(float4*)&Pc[o + s4] = pv;
    float4 sv = {h[s4], h[s4 + 1], h[s4 + 2], h[s4 + 3]};
    *(float4*)&Sc[o + s4] = sv;
  }
}

// ---------------- scan pass 1.5: stitch chunk partials into entry states ----------------
// thread = (b, d*DS+s); fold over chunks: h0[j] stored, then h = P_j*h + S_j.
__global__ __launch_bounds__(256) void scanmid_k(const float* __restrict__ Pc,
                                                 const float* __restrict__ Sc,
                                                 float* __restrict__ H0) {
  int idx = blockIdx.x * 256 + threadIdx.x;   // 0 .. BB*DI*DS-1
  int b   = idx >> 15;                        // DI*DS = 32768
  int e   = idx & (DI * DS - 1);
  size_t base = ((size_t)b * NC) * DI * DS + e;
  float h = 0.f;
#pragma unroll
  for (int j = 0; j < NC; ++j) {
    size_t o = base + (size_t)j * DI * DS;
    H0[o] = h;
    h = fmaf(Pc[o], h, Sc[o]);
  }
}

// ---------------- parallel selective scan, pass 2 (+ gate + bf16 cast) ----------------
// One lane per (b, d, chunk): load h0[16], re-scan own chunk emitting y.
__global__ __launch_bounds__(256) void scan2_k(const float* __restrict__ dt,
                                               const float* __restrict__ u,
                                               const float* __restrict__ BC,
                                               const float* __restrict__ xz,
                                               const float* __restrict__ A_log,
                                               const float* __restrict__ Dp,
                                               const float* __restrict__ H0,
                                               unsigned short* __restrict__ ymb) {
  int tid = threadIdx.x;
  int b   = blockIdx.y;
  int cg  = blockIdx.x / NC;
  int nc  = blockIdx.x % NC;
  int d   = cg * 256 + tid;
  float A2[DS], h[DS];
  size_t hb = (((size_t)b * NC + nc) * DI + d) * DS;
#pragma unroll
  for (int s4 = 0; s4 < DS; s4 += 4) {
    float4 av = *(const float4*)&A_log[d * DS + s4];
    A2[s4 + 0] = -expf(av.x) * 1.44269504f;
    A2[s4 + 1] = -expf(av.y) * 1.44269504f;
    A2[s4 + 2] = -expf(av.z) * 1.44269504f;
    A2[s4 + 3] = -expf(av.w) * 1.44269504f;
    float4 hv = *(const float4*)&H0[hb + s4];
    h[s4] = hv.x; h[s4 + 1] = hv.y; h[s4 + 2] = hv.z; h[s4 + 3] = hv.w;
  }
  float Dd = Dp[d];
  const int t0 = nc * LC;
  const float* dtp = dt + ((size_t)b * LL + t0) * DI + d;
  const float* up  = u  + ((size_t)b * LL + t0) * DI + d;
  const float* bcp = BC + ((size_t)b * LL + t0) * 32;     // wave-uniform -> SGPR
  const float* zp  = xz + ((size_t)b * LL + t0) * 4096 + DI + d;
  unsigned short* yp = ymb + ((size_t)b * LL + t0) * DI + d;
  for (int t = 0; t < LC; ++t) {
    float dtv = dtp[(size_t)t * DI];
    float uv  = up[(size_t)t * DI];
    float dtu = dtv * uv;
    float y   = 0.f;
#pragma unroll
    for (int s = 0; s < DS; ++s) {
      float dA = exp2f(dtv * A2[s]);
      h[s] = fmaf(dA, h[s], dtu * bcp[t * 32 + s]);
      y = fmaf(h[s], bcp[t * 32 + 16 + s], y);
    }
    float zv = zp[(size_t)t * 4096];
    y = fmaf(Dd, uv, y);
    float sz = zv / (1.f + expf(-zv));
    yp[(size_t)t * DI] = f2bf(y * sz);
  }
}

extern "C" void kernel_launch(void* const* d_in, const int* in_sizes, int n_in,
                              void* d_out, int out_size, void* d_ws, size_t ws_size,
                              hipStream_t stream) {
  const float* x      = (const float*)d_in[0];
  const float* W_in   = (const float*)d_in[1];
  const float* conv_w = (const float*)d_in[2];
  const float* conv_b = (const float*)d_in[3];
  const float* W_x    = (const float*)d_in[4];
  const float* W_dt   = (const float*)d_in[5];
  const float* b_dt   = (const float*)d_in[6];
  const float* A_log  = (const float*)d_in[7];
  const float* Dv     = (const float*)d_in[8];
  const float* W_out  = (const float*)d_in[9];
  float* out = (float*)d_out;

  // workspace carve-up (~213 MB)
  char* w = (char*)d_ws;
  float* xz  = (float*)w;            w += (size_t)MM * 4096 * 4;   // 64 MB
  float* xc  = (float*)w;            w += (size_t)MM * DI * 4;     // 32 MB
  float* dtb = (float*)w;            w += (size_t)MM * DI * 4;     // 32 MB
  float* BC  = (float*)w;            w += (size_t)MM * 32 * 4;     // 0.5 MB
  float* Pc  = (float*)w;            w += (size_t)BB * NC * DI * DS * 4;  // 8 MB
  float* Sc  = (float*)w;            w += (size_t)BB * NC * DI * DS * 4;  // 8 MB
  float* H0  = (float*)w;            w += (size_t)BB * NC * DI * DS * 4;  // 8 MB
  unsigned short* x_b   = (unsigned short*)w; w += (size_t)MM * DM * 2;    // 8 MB
  unsigned short* xc_b  = (unsigned short*)w; w += (size_t)MM * DI * 2;    // 16 MB
  unsigned short* ym_b  = (unsigned short*)w; w += (size_t)MM * DI * 2;    // 16 MB
  unsigned short* WinT  = (unsigned short*)w; w += (size_t)(2 * DI) * DM * 2;  // 8 MB
  unsigned short* WcatT = (unsigned short*)w; w += (size_t)NCAT * DI * 2;      // 8.5 MB
  unsigned short* WoutT = (unsigned short*)w; w += (size_t)DM * DI * 2;        // 4 MB

  // 1) casts + weight transposes (bf16, B^T layout for gemm_bt)
  cast_bf16_k<<<(MM * DM) / 1024, 256, 0, stream>>>(x, x_b, MM * DM);
  transpose_cast_k<<<dim3(4096 / 32, DM / 32), dim3(32, 8), 0, stream>>>(W_in, WinT, DM, 4096);
  transpose_cast_k<<<dim3(DI / 32, DI / 32), dim3(32, 8), 0, stream>>>(W_dt, WcatT, DI, DI);
  transpose_cast_k<<<dim3(1, DI / 32), dim3(32, 8), 0, stream>>>(W_x, WcatT + (size_t)DI * DI, DI, 32);
  hipMemsetAsync(WcatT + (size_t)(DI + 32) * DI, 0, (size_t)(NCAT - DI - 32) * DI * 2, stream);
  transpose_cast_k<<<dim3(DM / 32, DI / 32), dim3(32, 8), 0, stream>>>(W_out, WoutT, DI, DM);

  // 2) xz = x @ W_in   (4096 x 4096, K=1024)
  gemm_bt_k<0><<<(MM / BM) * (4096 / BN), 256, 0, stream>>>(x_b, WinT, xz, MM, 4096, DM,
                                                            nullptr, nullptr, 0);
  // 3) xc = silu(conv(xp))  -- 4 channels per thread
  conv_silu_k<<<(MM * DI) / 1024, 256, 0, stream>>>(xz, conv_w, conv_b, xc, xc_b);

  // 4) [dt | BC] = xc @ [W_dt | W_x] with softplus+bias epilogue on dt half
  gemm_bt_k<1><<<(MM / BM) * (NCAT / BN), 256, 0, stream>>>(xc_b, WcatT, dtb, MM, NCAT, DI,
                                                            b_dt, BC, DI);
  // 5) chunked parallel selective scan (reg-state) + D*u + silu(z) gate -> ym (bf16)
  scan1_k<<<dim3((DI / 256) * NC, BB), 256, 0, stream>>>(dtb, xc, BC, A_log, Pc, Sc);
  scanmid_k<<<(BB * DI * DS) / 256, 256, 0, stream>>>(Pc, Sc, H0);
  scan2_k<<<dim3((DI / 256) * NC, BB), 256, 0, stream>>>(dtb, xc, BC, xz, A_log, Dv, H0, ym_b);

  // 6) out = ym @ W_out  (4096 x 1024, K=2048)
  gemm_bt_k<0><<<(MM / BM) * (DM / BN), 256, 0, stream>>>(ym_b, WoutT, out, MM, DM, DI,
                                                          nullptr, nullptr, 0);
}

// Round 9
// 452.139 us; speedup vs baseline: 1.4541x; 1.0831x over previous
//
#include <hip/hip_runtime.h>
#include <hip/hip_bf16.h>
#include <cstdint>
#include <cstddef>

// Problem constants (match reference)
#define BB 2
#define LL 2048
#define DM 1024
#define DI 2048
#define DS 16
#define MM (BB*LL)       // 4096 rows
#define NCAT 2176        // 2048 (W_dt) + 32 (W_x) + 96 pad -> 17 tiles of 128
#define NC 32            // scan chunks (parallel-scan over L)
#define LC (LL/NC)       // 64 timesteps per chunk

typedef __attribute__((ext_vector_type(8))) short short8;   // 8 x bf16 fragment
typedef __attribute__((ext_vector_type(4))) float f32x4;    // MFMA accumulator

__device__ __forceinline__ unsigned short f2bf(float f) {
  union { float f; unsigned int u; } x; x.f = f;
  unsigned int u = x.u;
  unsigned int r = (u + 0x7FFFu + ((u >> 16) & 1u)) >> 16;  // RNE
  return (unsigned short)r;
}

// ---------------- cast fp32 -> bf16 (vectorized) ----------------
__global__ __launch_bounds__(256) void cast_bf16_k(const float* __restrict__ in,
                                                   unsigned short* __restrict__ out, int n) {
  int i = (blockIdx.x * 256 + threadIdx.x) * 4;
  if (i < n) {
    float4 v = *(const float4*)&in[i];
    ushort4 o;
    o.x = f2bf(v.x); o.y = f2bf(v.y); o.z = f2bf(v.z); o.w = f2bf(v.w);
    *(ushort4*)&out[i] = o;
  }
}

// ---------------- transpose + cast: W (RxC f32) -> WT (CxR bf16) ----------------
__global__ __launch_bounds__(256) void transpose_cast_k(const float* __restrict__ W,
                                                        unsigned short* __restrict__ WT,
                                                        int R, int C) {
  __shared__ float tile[32][33];
  int c0 = blockIdx.x * 32;
  int r0 = blockIdx.y * 32;
  int tx = threadIdx.x;        // 0..31
  int ty = threadIdx.y;        // 0..7
#pragma unroll
  for (int i = 0; i < 4; ++i) {
    int r = r0 + ty + i * 8;
    tile[ty + i * 8][tx] = W[(size_t)r * C + c0 + tx];
  }
  __syncthreads();
#pragma unroll
  for (int i = 0; i < 4; ++i) {
    int c = c0 + ty + i * 8;
    WT[(size_t)c * R + r0 + tx] = f2bf(tile[tx][ty + i * 8]);
  }
}

// ---------------- bf16 MFMA GEMM, C = A * Bt^T (2-phase LDS double-buffer) ----------------
// A: M x K bf16 row-major. Bt: N x K bf16 row-major.
// K-loop: issue STAGE(buf^1, kt+1) -> ds_read+MFMA on buf -> one __syncthreads
// (drains vmcnt AFTER compute, so global_load_lds latency hides under MFMA).
#define BM 128
#define BN 128
#define BK 32
template <int MODE>
__global__ __launch_bounds__(256) void gemm_bt_k(const unsigned short* __restrict__ A,
                                                 const unsigned short* __restrict__ Bt,
                                                 float* __restrict__ C,
                                                 int M, int N, int K,
                                                 const float* __restrict__ bias,
                                                 float* __restrict__ C2, int nSplit) {
  __shared__ unsigned short As[2][BM * BK];   // 2 x 8 KB
  __shared__ unsigned short Bs[2][BN * BK];   // 2 x 8 KB
  const int tid  = threadIdx.x;
  const int lane = tid & 63;
  const int wv   = tid >> 6;               // wave 0..3
  const int nTilesN = N / BN;
  const int bm = (blockIdx.x / nTilesN) * BM;
  const int bn = (blockIdx.x % nTilesN) * BN;
  const int wr = wv >> 1, wc = wv & 1;     // 2x2 wave grid, each wave 64x64

  // per-thread staging geometry (wave-uniform LDS dest + lane*16B)
  const int chunk0 = wv;                   // chunks wv and wv+4
  const int eidx0  = chunk0 * 64 + lane;
  const int row0   = eidx0 >> 2;
  const int col0   = (eidx0 & 3) * 8;
  const int chunk1 = wv + 4;
  const int eidx1  = chunk1 * 64 + lane;
  const int row1   = eidx1 >> 2;
  const int col1   = (eidx1 & 3) * 8;
  const unsigned short* gA0 = A  + (size_t)(bm + row0) * K + col0;
  const unsigned short* gB0 = Bt + (size_t)(bn + row0) * K + col0;
  const unsigned short* gA1 = A  + (size_t)(bm + row1) * K + col1;
  const unsigned short* gB1 = Bt + (size_t)(bn + row1) * K + col1;

#define STAGE(buf, k0)                                                              \
  do {                                                                              \
    __builtin_amdgcn_global_load_lds(                                               \
        (const __attribute__((address_space(1))) unsigned int*)(gA0 + (k0)),        \
        (__attribute__((address_space(3))) unsigned int*)&As[buf][chunk0 * 512],    \
        16, 0, 0);                                                                  \
    __builtin_amdgcn_global_load_lds(                                               \
        (const __attribute__((address_space(1))) unsigned int*)(gB0 + (k0)),        \
        (__attribute__((address_space(3))) unsigned int*)&Bs[buf][chunk0 * 512],    \
        16, 0, 0);                                                                  \
    __builtin_amdgcn_global_load_lds(                                               \
        (const __attribute__((address_space(1))) unsigned int*)(gA1 + (k0)),        \
        (__attribute__((address_space(3))) unsigned int*)&As[buf][chunk1 * 512],    \
        16, 0, 0);                                                                  \
    __builtin_amdgcn_global_load_lds(                                               \
        (const __attribute__((address_space(1))) unsigned int*)(gB1 + (k0)),        \
        (__attribute__((address_space(3))) unsigned int*)&Bs[buf][chunk1 * 512],    \
        16, 0, 0);                                                                  \
  } while (0)

  f32x4 acc[4][4] = {};

  const int nK = K / BK;
  STAGE(0, 0);
  __syncthreads();                         // drain prologue stage
  int cur = 0;
  for (int kt = 0; kt < nK; ++kt) {
    if (kt + 1 < nK) STAGE(cur ^ 1, (kt + 1) * BK);   // prefetch next tile

    short8 af[4], bf[4];
    const int kofs = (lane >> 4) * 8;
#pragma unroll
    for (int i = 0; i < 4; ++i) {
      int ar = wr * 64 + i * 16 + (lane & 15);
      af[i] = *(const short8*)&As[cur][ar * BK + kofs];
      int br = wc * 64 + i * 16 + (lane & 15);
      bf[i] = *(const short8*)&Bs[cur][br * BK + kofs];
    }
#pragma unroll
    for (int i = 0; i < 4; ++i)
#pragma unroll
      for (int j = 0; j < 4; ++j)
        acc[i][j] = __builtin_amdgcn_mfma_f32_16x16x32_bf16(af[i], bf[j], acc[i][j], 0, 0, 0);

    __syncthreads();                       // drains vmcnt (stage done) + lgkm; one barrier/iter
    cur ^= 1;
  }
#undef STAGE

  // epilogue: C/D layout col = lane&15, row = (lane>>4)*4 + r
  const int colBase = bn + wc * 64;
  const int rowBase = bm + wr * 64;
#pragma unroll
  for (int i = 0; i < 4; ++i) {
#pragma unroll
    for (int j = 0; j < 4; ++j) {
      int c = colBase + j * 16 + (lane & 15);
#pragma unroll
      for (int r4 = 0; r4 < 4; ++r4) {
        int rr = rowBase + i * 16 + (lane >> 4) * 4 + r4;
        float v = acc[i][j][r4];
        if (MODE == 0) {
          C[(size_t)rr * N + c] = v;
        } else {
          if (c < nSplit) {
            float t = v + bias[c];
            C[(size_t)rr * nSplit + c] = (t > 20.f) ? t : log1pf(expf(t));
          } else if (c < nSplit + 32) {
            C2[(size_t)rr * 32 + (c - nSplit)] = v;
          }
        }
      }
    }
  }
}

// ---------------- causal depthwise conv (K=4) + SiLU, x4 channels/thread ----------------
__global__ __launch_bounds__(256) void conv_silu_k(const float* __restrict__ xz,
                                                   const float* __restrict__ cw,
                                                   const float* __restrict__ cb,
                                                   float* __restrict__ xc,
                                                   unsigned short* __restrict__ xcb) {
  int idx = blockIdx.x * 256 + threadIdx.x;          // B*L*DI/4 threads
  int i4  = idx * 4;
  int c4  = i4 & (DI - 1);                           // channel base (multiple of 4)
  int row = i4 >> 11;                                // b*L + t
  int t   = row & (LL - 1);
  size_t base = (size_t)row * 4096 + c4;
  float4 x3 = *(const float4*)&xz[base];             // tap at l (w3)
  float4 x2 = (t >= 1) ? *(const float4*)&xz[base - 4096]  : float4{0, 0, 0, 0};
  float4 x1 = (t >= 2) ? *(const float4*)&xz[base - 8192]  : float4{0, 0, 0, 0};
  float4 x0 = (t >= 3) ? *(const float4*)&xz[base - 12288] : float4{0, 0, 0, 0};
  float4 bias = *(const float4*)&cb[c4];
  float4 w[4];
#pragma unroll
  for (int j = 0; j < 4; ++j) w[j] = *(const float4*)&cw[(c4 + j) * 4];
  float vx3[4] = {x3.x, x3.y, x3.z, x3.w};
  float vx2[4] = {x2.x, x2.y, x2.z, x2.w};
  float vx1[4] = {x1.x, x1.y, x1.z, x1.w};
  float vx0[4] = {x0.x, x0.y, x0.z, x0.w};
  float vb[4]  = {bias.x, bias.y, bias.z, bias.w};
  float4 so;
  ushort4 sb;
  float res[4];
#pragma unroll
  for (int j = 0; j < 4; ++j) {
    float v = vb[j];
    v = fmaf(vx3[j], w[j].w, v);
    v = fmaf(vx2[j], w[j].z, v);
    v = fmaf(vx1[j], w[j].y, v);
    v = fmaf(vx0[j], w[j].x, v);
    res[j] = v / (1.f + expf(-v));                   // SiLU
  }
  so.x = res[0]; so.y = res[1]; so.z = res[2]; so.w = res[3];
  sb.x = f2bf(res[0]); sb.y = f2bf(res[1]); sb.z = f2bf(res[2]); sb.w = f2bf(res[3]);
  *(float4*)&xc[i4] = so;
  *(ushort4*)&xcb[i4] = sb;
}

// ---------------- parallel selective scan, pass 1 ----------------
__global__ __launch_bounds__(256) void scan1_k(const float* __restrict__ dt,
                                               const float* __restrict__ u,
                                               const float* __restrict__ BC,
                                               const float* __restrict__ A_log,
                                               float* __restrict__ Pc,
                                               float* __restrict__ Sc) {
  int tid = threadIdx.x;
  int b   = blockIdx.y;
  int cg  = blockIdx.x / NC;           // channel group of 256
  int nc  = blockIdx.x % NC;           // chunk
  int d   = cg * 256 + tid;
  float A2[DS], h[DS];
#pragma unroll
  for (int s4 = 0; s4 < DS; s4 += 4) {
    float4 av = *(const float4*)&A_log[d * DS + s4];
    A2[s4 + 0] = -expf(av.x) * 1.44269504f;
    A2[s4 + 1] = -expf(av.y) * 1.44269504f;
    A2[s4 + 2] = -expf(av.z) * 1.44269504f;
    A2[s4 + 3] = -expf(av.w) * 1.44269504f;
    h[s4] = 0.f; h[s4 + 1] = 0.f; h[s4 + 2] = 0.f; h[s4 + 3] = 0.f;
  }
  float Tsum = 0.f;
  const int t0 = nc * LC;
  const float* dtp = dt + ((size_t)b * LL + t0) * DI + d;
  const float* up  = u  + ((size_t)b * LL + t0) * DI + d;
  const float* bcp = BC + ((size_t)b * LL + t0) * 32;     // wave-uniform -> SGPR
  for (int t = 0; t < LC; ++t) {
    float dtv = dtp[(size_t)t * DI];
    float uv  = up[(size_t)t * DI];
    float dtu = dtv * uv;
    Tsum += dtv;
#pragma unroll
    for (int s = 0; s < DS; ++s) {
      float dA = exp2f(dtv * A2[s]);
      h[s] = fmaf(dA, h[s], dtu * bcp[t * 32 + s]);
    }
  }
  size_t o = (((size_t)b * NC + nc) * DI + d) * DS;
#pragma unroll
  for (int s4 = 0; s4 < DS; s4 += 4) {
    float4 pv = {exp2f(A2[s4] * Tsum), exp2f(A2[s4 + 1] * Tsum),
                 exp2f(A2[s4 + 2] * Tsum), exp2f(A2[s4 + 3] * Tsum)};
    *(float4*)&Pc[o + s4] = pv;
    float4 sv = {h[s4], h[s4 + 1], h[s4 + 2], h[s4 + 3]};
    *(float4*)&Sc[o + s4] = sv;
  }
}

// ---------------- scan pass 1.5: stitch chunk partials into entry states ----------------
__global__ __launch_bounds__(256) void scanmid_k(const float* __restrict__ Pc,
                                                 const float* __restrict__ Sc,
                                                 float* __restrict__ H0) {
  int idx = blockIdx.x * 256 + threadIdx.x;   // 0 .. BB*DI*DS-1
  int b   = idx >> 15;                        // DI*DS = 32768
  int e   = idx & (DI * DS - 1);
  size_t base = ((size_t)b * NC) * DI * DS + e;
  float h = 0.f;
#pragma unroll
  for (int j = 0; j < NC; ++j) {
    size_t o = base + (size_t)j * DI * DS;
    H0[o] = h;
    h = fmaf(Pc[o], h, Sc[o]);
  }
}

// ---------------- parallel selective scan, pass 2 (+ gate + bf16 cast) ----------------
__global__ __launch_bounds__(256) void scan2_k(const float* __restrict__ dt,
                                               const float* __restrict__ u,
                                               const float* __restrict__ BC,
                                               const float* __restrict__ xz,
                                               const float* __restrict__ A_log,
                                               const float* __restrict__ Dp,
                                               const float* __restrict__ H0,
                                               unsigned short* __restrict__ ymb) {
  int tid = threadIdx.x;
  int b   = blockIdx.y;
  int cg  = blockIdx.x / NC;
  int nc  = blockIdx.x % NC;
  int d   = cg * 256 + tid;
  float A2[DS], h[DS];
  size_t hb = (((size_t)b * NC + nc) * DI + d) * DS;
#pragma unroll
  for (int s4 = 0; s4 < DS; s4 += 4) {
    float4 av = *(const float4*)&A_log[d * DS + s4];
    A2[s4 + 0] = -expf(av.x) * 1.44269504f;
    A2[s4 + 1] = -expf(av.y) * 1.44269504f;
    A2[s4 + 2] = -expf(av.z) * 1.44269504f;
    A2[s4 + 3] = -expf(av.w) * 1.44269504f;
    float4 hv = *(const float4*)&H0[hb + s4];
    h[s4] = hv.x; h[s4 + 1] = hv.y; h[s4 + 2] = hv.z; h[s4 + 3] = hv.w;
  }
  float Dd = Dp[d];
  const int t0 = nc * LC;
  const float* dtp = dt + ((size_t)b * LL + t0) * DI + d;
  const float* up  = u  + ((size_t)b * LL + t0) * DI + d;
  const float* bcp = BC + ((size_t)b * LL + t0) * 32;     // wave-uniform -> SGPR
  const float* zp  = xz + ((size_t)b * LL + t0) * 4096 + DI + d;
  unsigned short* yp = ymb + ((size_t)b * LL + t0) * DI + d;
  for (int t = 0; t < LC; ++t) {
    float dtv = dtp[(size_t)t * DI];
    float uv  = up[(size_t)t * DI];
    float dtu = dtv * uv;
    float y   = 0.f;
#pragma unroll
    for (int s = 0; s < DS; ++s) {
      float dA = exp2f(dtv * A2[s]);
      h[s] = fmaf(dA, h[s], dtu * bcp[t * 32 + s]);
      y = fmaf(h[s], bcp[t * 32 + 16 + s], y);
    }
    float zv = zp[(size_t)t * 4096];
    y = fmaf(Dd, uv, y);
    float sz = zv / (1.f + expf(-zv));
    yp[(size_t)t * DI] = f2bf(y * sz);
  }
}

extern "C" void kernel_launch(void* const* d_in, const int* in_sizes, int n_in,
                              void* d_out, int out_size, void* d_ws, size_t ws_size,
                              hipStream_t stream) {
  const float* x      = (const float*)d_in[0];
  const float* W_in   = (const float*)d_in[1];
  const float* conv_w = (const float*)d_in[2];
  const float* conv_b = (const float*)d_in[3];
  const float* W_x    = (const float*)d_in[4];
  const float* W_dt   = (const float*)d_in[5];
  const float* b_dt   = (const float*)d_in[6];
  const float* A_log  = (const float*)d_in[7];
  const float* Dv     = (const float*)d_in[8];
  const float* W_out  = (const float*)d_in[9];
  float* out = (float*)d_out;

  // workspace carve-up (~213 MB)
  char* w = (char*)d_ws;
  float* xz  = (float*)w;            w += (size_t)MM * 4096 * 4;   // 64 MB
  float* xc  = (float*)w;            w += (size_t)MM * DI * 4;     // 32 MB
  float* dtb = (float*)w;            w += (size_t)MM * DI * 4;     // 32 MB
  float* BC  = (float*)w;            w += (size_t)MM * 32 * 4;     // 0.5 MB
  float* Pc  = (float*)w;            w += (size_t)BB * NC * DI * DS * 4;  // 8 MB
  float* Sc  = (float*)w;            w += (size_t)BB * NC * DI * DS * 4;  // 8 MB
  float* H0  = (float*)w;            w += (size_t)BB * NC * DI * DS * 4;  // 8 MB
  unsigned short* x_b   = (unsigned short*)w; w += (size_t)MM * DM * 2;    // 8 MB
  unsigned short* xc_b  = (unsigned short*)w; w += (size_t)MM * DI * 2;    // 16 MB
  unsigned short* ym_b  = (unsigned short*)w; w += (size_t)MM * DI * 2;    // 16 MB
  unsigned short* WinT  = (unsigned short*)w; w += (size_t)(2 * DI) * DM * 2;  // 8 MB
  unsigned short* WcatT = (unsigned short*)w; w += (size_t)NCAT * DI * 2;      // 8.5 MB
  unsigned short* WoutT = (unsigned short*)w; w += (size_t)DM * DI * 2;        // 4 MB

  // 1) casts + weight transposes (bf16, B^T layout for gemm_bt)
  cast_bf16_k<<<(MM * DM) / 1024, 256, 0, stream>>>(x, x_b, MM * DM);
  transpose_cast_k<<<dim3(4096 / 32, DM / 32), dim3(32, 8), 0, stream>>>(W_in, WinT, DM, 4096);
  transpose_cast_k<<<dim3(DI / 32, DI / 32), dim3(32, 8), 0, stream>>>(W_dt, WcatT, DI, DI);
  transpose_cast_k<<<dim3(1, DI / 32), dim3(32, 8), 0, stream>>>(W_x, WcatT + (size_t)DI * DI, DI, 32);
  hipMemsetAsync(WcatT + (size_t)(DI + 32) * DI, 0, (size_t)(NCAT - DI - 32) * DI * 2, stream);
  transpose_cast_k<<<dim3(DM / 32, DI / 32), dim3(32, 8), 0, stream>>>(W_out, WoutT, DI, DM);

  // 2) xz = x @ W_in   (4096 x 4096, K=1024)
  gemm_bt_k<0><<<(MM / BM) * (4096 / BN), 256, 0, stream>>>(x_b, WinT, xz, MM, 4096, DM,
                                                            nullptr, nullptr, 0);
  // 3) xc = silu(conv(xp))  -- 4 channels per thread
  conv_silu_k<<<(MM * DI) / 1024, 256, 0, stream>>>(xz, conv_w, conv_b, xc, xc_b);

  // 4) [dt | BC] = xc @ [W_dt | W_x] with softplus+bias epilogue on dt half
  gemm_bt_k<1><<<(MM / BM) * (NCAT / BN), 256, 0, stream>>>(xc_b, WcatT, dtb, MM, NCAT, DI,
                                                            b_dt, BC, DI);
  // 5) chunked parallel selective scan (reg-state) + D*u + silu(z) gate -> ym (bf16)
  scan1_k<<<dim3((DI / 256) * NC, BB), 256, 0, stream>>>(dtb, xc, BC, A_log, Pc, Sc);
  scanmid_k<<<(BB * DI * DS) / 256, 256, 0, stream>>>(Pc, Sc, H0);
  scan2_k<<<dim3((DI / 256) * NC, BB), 256, 0, stream>>>(dtb, xc, BC, xz, A_log, Dv, H0, ym_b);

  // 6) out = ym @ W_out  (4096 x 1024, K=2048)
  gemm_bt_k<0><<<(MM / BM) * (DM / BN), 256, 0, stream>>>(ym_b, WoutT, out, MM, DM, DI,
                                                          nullptr, nullptr, 0);
}